// Round 2
// baseline (52.670 us; speedup 1.0000x reference)
//
#include <hip/hip_runtime.h>

#define CIN   32
#define COUT  64
#define XG    256
#define ZG    256

// One 64-lane wave per point. lane = output channel.
// acc[lane] = sum_i feats[n][i] * kernel[idx[n]][i][lane]
// then atomic scatter-add into bev[lin[n]][lane].
__global__ __launch_bounds__(256) void tobev_kernel(
    const float* __restrict__ feats,
    const int*   __restrict__ coords,
    const float* __restrict__ kern,
    float* __restrict__ out,
    int n)
{
    const int wid  = blockIdx.x * 4 + (threadIdx.x >> 6);
    const int lane = threadIdx.x & 63;
    if (wid >= n) return;

    // coords row: [x, y, z, b]
    const int4 c = *reinterpret_cast<const int4*>(coords + wid * 4);
    const int idx = c.y;                               // STRIDE == 1
    const int lin = (c.w * XG + c.x) * ZG + c.z;

    // lanes 0..31 hold feats[wid][0..31]; lanes 32..63 duplicate (same lines)
    const float f = feats[wid * CIN + (lane & 31)];
    const float* __restrict__ w = kern + idx * (CIN * COUT) + lane;

    float acc = 0.f;
    #pragma unroll
    for (int i = 0; i < CIN; ++i) {
        const float fi = __shfl(f, i, 64);             // const lane -> v_readlane
        acc = fmaf(fi, w[(size_t)i * COUT], acc);
    }

    unsafeAtomicAdd(&out[(size_t)lin * COUT + lane], acc);
}

extern "C" void kernel_launch(void* const* d_in, const int* in_sizes, int n_in,
                              void* d_out, int out_size, void* d_ws, size_t ws_size,
                              hipStream_t stream) {
    const float* feats  = (const float*)d_in[0];
    const int*   coords = (const int*)d_in[1];
    const float* kern   = (const float*)d_in[2];
    float* out = (float*)d_out;

    const int n = in_sizes[0] / CIN;                   // N = 100000

    // segment_sum accumulator must start at zero every call
    hipMemsetAsync(d_out, 0, (size_t)out_size * sizeof(float), stream);

    const int blocks = (n + 3) / 4;                    // 4 waves (points) per block
    hipLaunchKernelGGL(tobev_kernel, dim3(blocks), dim3(256), 0, stream,
                       feats, coords, kern, out, n);
}